// Round 5
// baseline (59.436 us; speedup 1.0000x reference)
//
#include <hip/hip_runtime.h>

#define BATCH 2048
#define NTEACH 64

typedef __attribute__((ext_vector_type(8))) short short8;
typedef __attribute__((ext_vector_type(4))) float f32x4;

__device__ __forceinline__ unsigned short f2bf(float f) {
    unsigned u = __float_as_uint(f);
    u += 0x7FFFu + ((u >> 16) & 1u);          // round-to-nearest-even
    return (unsigned short)(u >> 16);
}

__device__ __forceinline__ short8 cvt8(float4 a, float4 b) {
    short8 r;
    r[0] = (short)f2bf(a.x); r[1] = (short)f2bf(a.y);
    r[2] = (short)f2bf(a.z); r[3] = (short)f2bf(a.w);
    r[4] = (short)f2bf(b.x); r[5] = (short)f2bf(b.y);
    r[6] = (short)f2bf(b.z); r[7] = (short)f2bf(b.w);
    return r;
}

// Fully fused per-teacher MLP. Block = (teacher, 32-row chunk), 1024 threads
// = 16 waves. Sample membership recomputed in-kernel (stable rank via ballot
// prefix over tidx). Activations live in LDS (bf16, XOR-swizzled rows);
// weights stream from global fp32 -> bf16 B-frags, each read once per block.
// MFMA 16x16x32: A row=lane&15, k=(lane>>4)*8+j; B col=lane&15 (= W row),
// same k; D col=lane&15, row=(lane>>4)*4+j.  [verified R2-R4]
__global__ __launch_bounds__(1024) void fused_mlp(
    const float* __restrict__ obs, const int* __restrict__ tidx,
    const float* __restrict__ w0, const float* __restrict__ b0,
    const float* __restrict__ w2, const float* __restrict__ b2,
    const float* __restrict__ w4, const float* __restrict__ b4,
    const float* __restrict__ w6, const float* __restrict__ b6,
    float* __restrict__ out) {
    __shared__ char hbuf[57344];          // h0 32x512 @0 (stride 1024B),
                                          // h1 32x256 @32768 (512B),
                                          // h2 32x128 @49152 (256B)
    __shared__ int wsum[16];
    __shared__ int ordc[32];

    char* h0b = hbuf;
    char* h1b = hbuf + 32768;
    char* h2b = hbuf + 49152;

    const int t = blockIdx.x;
    const int tid = threadIdx.x;
    const int lane = tid & 63;
    const int wid = tid >> 6;
    const int ln = lane & 15;
    const int kg = lane >> 4;

    for (int c = blockIdx.y;; c += gridDim.y) {
        const int cbase = c * 32;
        // ---------- in-kernel stable bucket scan ----------
        __syncthreads();                  // protects ordc/wsum/hbuf reuse
        int carry = 0;
#pragma unroll
        for (int r = 0; r < 2; ++r) {
            int i = r * 1024 + tid;
            bool f = (tidx[i] == t);
            unsigned long long b = __ballot(f);
            if (lane == 0) wsum[wid] = __builtin_popcountll(b);
            int below = __builtin_popcountll(b & ((1ull << lane) - 1ull));
            __syncthreads();
            int wbase = 0, tot = 0;
#pragma unroll
            for (int j = 0; j < 16; ++j) {
                int s = wsum[j];
                if (j < wid) wbase += s;
                tot += s;
            }
            int rank = carry + wbase + below;
            if (f && rank >= cbase && rank < cbase + 32) ordc[rank - cbase] = i;
            carry += tot;
            __syncthreads();
        }
        const int count = carry;
        if (cbase >= count) break;        // uniform: count identical on all threads
        const int nv = min(32, count - cbase);

        // ---------- L0: obs(48, pad 64) -> h0(512), gather + elu ----------
        {
            const int n0 = wid * 32;
            short8 bf[2][2];
#pragma unroll
            for (int nt = 0; nt < 2; ++nt) {
                const float* wr = w0 + ((size_t)t * 512 + n0 + nt * 16 + ln) * 48;
#pragma unroll
                for (int kt = 0; kt < 2; ++kt) {
                    int kb = kt * 32 + kg * 8;
                    short8 f8 = {0, 0, 0, 0, 0, 0, 0, 0};
                    if (kb < 48)
                        f8 = cvt8(*(const float4*)(wr + kb), *(const float4*)(wr + kb + 4));
                    bf[nt][kt] = f8;
                }
            }
#pragma unroll
            for (int mt = 0; mt < 2; ++mt) {
                int lr = mt * 16 + ln;
                int arow = (lr < nv) ? ordc[lr] : ordc[0];
                const float* xr = obs + (size_t)arow * 48;
                short8 af[2];
#pragma unroll
                for (int kt = 0; kt < 2; ++kt) {
                    int kb = kt * 32 + kg * 8;
                    short8 f8 = {0, 0, 0, 0, 0, 0, 0, 0};
                    if (kb < 48)
                        f8 = cvt8(*(const float4*)(xr + kb), *(const float4*)(xr + kb + 4));
                    af[kt] = f8;
                }
#pragma unroll
                for (int nt = 0; nt < 2; ++nt) {
                    f32x4 acc = {0.f, 0.f, 0.f, 0.f};
                    acc = __builtin_amdgcn_mfma_f32_16x16x32_bf16(af[0], bf[nt][0], acc, 0, 0, 0);
                    acc = __builtin_amdgcn_mfma_f32_16x16x32_bf16(af[1], bf[nt][1], acc, 0, 0, 0);
                    int col = n0 + nt * 16 + ln;
                    float bias = b0[(size_t)t * 512 + col];
#pragma unroll
                    for (int j = 0; j < 4; ++j) {
                        int row = mt * 16 + kg * 4 + j;
                        float v = acc[j] + bias;
                        v = v > 0.f ? v : expm1f(v);
                        int byte = (row * 1024 + col * 2) ^ ((row & 7) << 4);
                        *(unsigned short*)(h0b + byte) = f2bf(v);
                    }
                }
            }
        }
        __syncthreads();

        // ---------- L1: h0(512) -> h1(256), elu ----------
        {
            const int n0 = wid * 16;
            f32x4 acc[2] = {{0.f, 0.f, 0.f, 0.f}, {0.f, 0.f, 0.f, 0.f}};
#pragma unroll
            for (int kh = 0; kh < 2; ++kh) {          // two K halves: caps B VGPR at 32
                short8 bf[8];
                const float* wr = w2 + ((size_t)t * 256 + n0 + ln) * 512 + kh * 256;
#pragma unroll
                for (int k8 = 0; k8 < 8; ++k8) {
                    int kb = k8 * 32 + kg * 8;
                    bf[k8] = cvt8(*(const float4*)(wr + kb), *(const float4*)(wr + kb + 4));
                }
#pragma unroll
                for (int mt = 0; mt < 2; ++mt) {
                    int row = mt * 16 + ln;
#pragma unroll
                    for (int k8 = 0; k8 < 8; ++k8) {
                        int col0 = kh * 256 + k8 * 32 + kg * 8;
                        int byte = (row * 1024 + col0 * 2) ^ ((row & 7) << 4);
                        short8 af = *(const short8*)(h0b + byte);
                        acc[mt] = __builtin_amdgcn_mfma_f32_16x16x32_bf16(af, bf[k8], acc[mt], 0, 0, 0);
                    }
                }
            }
            int col = n0 + ln;
            float bias = b2[(size_t)t * 256 + col];
#pragma unroll
            for (int mt = 0; mt < 2; ++mt)
#pragma unroll
                for (int j = 0; j < 4; ++j) {
                    int row = mt * 16 + kg * 4 + j;
                    float v = acc[mt][j] + bias;
                    v = v > 0.f ? v : expm1f(v);
                    int byte = (row * 512 + col * 2) ^ ((row & 7) << 4);
                    *(unsigned short*)(h1b + byte) = f2bf(v);
                }
        }
        __syncthreads();

        // ---------- L2: h1(256) -> h2(128), elu ----------
        {
            const int nt = wid & 7, mt = wid >> 3;
            const int n0 = nt * 16;
            short8 bf[8];
            const float* wr = w4 + ((size_t)t * 128 + n0 + ln) * 256;
#pragma unroll
            for (int k8 = 0; k8 < 8; ++k8) {
                int kb = k8 * 32 + kg * 8;
                bf[k8] = cvt8(*(const float4*)(wr + kb), *(const float4*)(wr + kb + 4));
            }
            f32x4 acc = {0.f, 0.f, 0.f, 0.f};
            int row = mt * 16 + ln;
#pragma unroll
            for (int k8 = 0; k8 < 8; ++k8) {
                int col0 = k8 * 32 + kg * 8;
                int byte = (row * 512 + col0 * 2) ^ ((row & 7) << 4);
                short8 af = *(const short8*)(h1b + byte);
                acc = __builtin_amdgcn_mfma_f32_16x16x32_bf16(af, bf[k8], acc, 0, 0, 0);
            }
            int col = n0 + ln;
            float bias = b4[(size_t)t * 128 + col];
#pragma unroll
            for (int j = 0; j < 4; ++j) {
                int orow = mt * 16 + kg * 4 + j;
                float v = acc[j] + bias;
                v = v > 0.f ? v : expm1f(v);
                int byte = (orow * 256 + col * 2) ^ ((orow & 7) << 4);
                *(unsigned short*)(h2b + byte) = f2bf(v);
            }
        }
        __syncthreads();

        // ---------- final: h2(128) -> out(12), tanh, scatter ----------
        if (wid < 2) {
            const int mt = wid;
            short8 bf[4];
            const float* wr = w6 + ((size_t)t * 12 + (ln < 12 ? ln : 0)) * 128;
#pragma unroll
            for (int kt = 0; kt < 4; ++kt) {
                int kb = kt * 32 + kg * 8;
                bf[kt] = cvt8(*(const float4*)(wr + kb), *(const float4*)(wr + kb + 4));
            }
            f32x4 acc = {0.f, 0.f, 0.f, 0.f};
            int row = mt * 16 + ln;
#pragma unroll
            for (int kt = 0; kt < 4; ++kt) {
                int col0 = kt * 32 + kg * 8;
                int byte = (row * 256 + col0 * 2) ^ ((row & 7) << 4);
                short8 af = *(const short8*)(h2b + byte);
                acc = __builtin_amdgcn_mfma_f32_16x16x32_bf16(af, bf[kt], acc, 0, 0, 0);
            }
            float bias = (ln < 12) ? b6[(size_t)t * 12 + ln] : 0.f;
#pragma unroll
            for (int j = 0; j < 4; ++j) {
                int orow = mt * 16 + kg * 4 + j;
                if (ln < 12 && cbase + orow < count)
                    out[(size_t)ordc[orow] * 12 + ln] = tanhf(acc[j] + bias);
            }
        }
    }
}

extern "C" void kernel_launch(void* const* d_in, const int* in_sizes, int n_in,
                              void* d_out, int out_size, void* d_ws, size_t ws_size,
                              hipStream_t stream) {
    const float* obs = (const float*)d_in[0];
    const int* tidx  = (const int*)d_in[1];
    const float* w0  = (const float*)d_in[2];
    const float* b0  = (const float*)d_in[3];
    const float* w2  = (const float*)d_in[4];
    const float* b2  = (const float*)d_in[5];
    const float* w4  = (const float*)d_in[6];
    const float* b4  = (const float*)d_in[7];
    const float* w6  = (const float*)d_in[8];
    const float* b6  = (const float*)d_in[9];
    float* out = (float*)d_out;

    // One kernel, no workspace: 64 teachers x 4 chunks of 32 rows (chunk loop
    // inside covers any sample distribution).
    fused_mlp<<<dim3(NTEACH, 4), 1024, 0, stream>>>(obs, tidx, w0, b0, w2, b2,
                                                    w4, b4, w6, b6, out);
}

// Round 6
// 40.536 us; speedup vs baseline: 1.4663x; 1.4663x over previous
//
#include <hip/hip_runtime.h>

#define BATCH 2048
#define NTEACH 64

typedef __attribute__((ext_vector_type(8))) short short8;
typedef __attribute__((ext_vector_type(4))) float f32x4;

__device__ __forceinline__ unsigned short f2bf(float f) {
    unsigned u = __float_as_uint(f);
    u += 0x7FFFu + ((u >> 16) & 1u);          // round-to-nearest-even
    return (unsigned short)(u >> 16);
}

__device__ __forceinline__ short8 cvt8(float4 a, float4 b) {
    short8 r;
    r[0] = (short)f2bf(a.x); r[1] = (short)f2bf(a.y);
    r[2] = (short)f2bf(a.z); r[3] = (short)f2bf(a.w);
    r[4] = (short)f2bf(b.x); r[5] = (short)f2bf(b.y);
    r[6] = (short)f2bf(b.z); r[7] = (short)f2bf(b.w);
    return r;
}

// Block-wide (256 thr) scan of tidx for teacher t. Returns (start, count):
// start = #samples with teacher < t, count = #samples with teacher == t.
// If ord != nullptr (LDS, BATCH ints), fills ord[0..count) with the stable
// original-index list for teacher t. Uniform result; 16 barriers total.
__device__ __forceinline__ int2 scan_teacher(const int* __restrict__ tidx,
                                             int t, int* ord) {
    __shared__ int ws_[4];
    const int tid = threadIdx.x;
    const int lane = tid & 63;
    const int wid = tid >> 6;
    int base = 0;
    int my_lt = 0;
#pragma unroll
    for (int r = 0; r < 8; ++r) {
        int i = r * 256 + tid;
        int v = tidx[i];
        bool f = (v == t);
        my_lt += (v < t) ? 1 : 0;
        unsigned long long b = __ballot(f);
        if (lane == 0) ws_[wid] = __builtin_popcountll(b);
        int below = __builtin_popcountll(b & ((1ull << lane) - 1ull));
        __syncthreads();
        int w0 = ws_[0], w1 = ws_[1], w2 = ws_[2], w3 = ws_[3];
        if (ord && f) {
            int wbase = (wid > 0 ? w0 : 0) + (wid > 1 ? w1 : 0) + (wid > 2 ? w2 : 0);
            ord[base + wbase + below] = i;
        }
        base += w0 + w1 + w2 + w3;
        __syncthreads();
    }
    for (int off = 32; off; off >>= 1) my_lt += __shfl_down(my_lt, off);
    if (lane == 0) ws_[wid] = my_lt;
    __syncthreads();
    int start = ws_[0] + ws_[1] + ws_[2] + ws_[3];
    __syncthreads();
    return make_int2(start, base);
}

// ---------- L0: obs(48) -> h0(512) bf16 sorted, gather + elu ----------
// grid (16 n-tiles, 64 t); 4 waves = N2 x M2. MFMA 16x16x32 bf16:
// A row=lane&15, k=(lane>>4)*8+j; B col=lane&15; D col=lane&15, row=(lane>>4)*4+j.
__global__ __launch_bounds__(256) void l0_kernel(const float* __restrict__ obs,
                                                 const int* __restrict__ tidx,
                                                 const float* __restrict__ w0,
                                                 const float* __restrict__ b0,
                                                 unsigned short* __restrict__ h0) {
    __shared__ int ord[BATCH];
    const int t = blockIdx.y;
    int2 sc = scan_teacher(tidx, t, ord);
    const int start = sc.x, count = sc.y;
    if (count == 0) return;
    const int lane = threadIdx.x & 63, wid = threadIdx.x >> 6;
    const int ln = lane & 15, kg = lane >> 4;
    const int nq = wid & 1, mq = wid >> 1;
    const int n0 = blockIdx.x * 32 + nq * 16;

    short8 bf[2];
    const float* wr = w0 + ((size_t)t * 512 + n0 + ln) * 48;
#pragma unroll
    for (int kt = 0; kt < 2; ++kt) {
        int kb = kt * 32 + kg * 8;
        short8 f8 = {0, 0, 0, 0, 0, 0, 0, 0};
        if (kb < 48) f8 = cvt8(*(const float4*)(wr + kb), *(const float4*)(wr + kb + 4));
        bf[kt] = f8;
    }
    const float bias = b0[(size_t)t * 512 + n0 + ln];

    for (int r0 = mq * 16; r0 < count; r0 += 32) {
        int lr = r0 + ln;
        const float* xr = obs + (size_t)ord[lr < count ? lr : 0] * 48;
        short8 af[2];
#pragma unroll
        for (int kt = 0; kt < 2; ++kt) {
            int kb = kt * 32 + kg * 8;
            short8 f8 = {0, 0, 0, 0, 0, 0, 0, 0};
            if (kb < 48) f8 = cvt8(*(const float4*)(xr + kb), *(const float4*)(xr + kb + 4));
            af[kt] = f8;
        }
        f32x4 acc = {0.f, 0.f, 0.f, 0.f};
        acc = __builtin_amdgcn_mfma_f32_16x16x32_bf16(af[0], bf[0], acc, 0, 0, 0);
        acc = __builtin_amdgcn_mfma_f32_16x16x32_bf16(af[1], bf[1], acc, 0, 0, 0);
#pragma unroll
        for (int j = 0; j < 4; ++j) {
            int row = r0 + kg * 4 + j;
            if (row < count) {
                float v = acc[j] + bias;
                v = v > 0.f ? v : expm1f(v);
                h0[(size_t)(start + row) * 512 + n0 + ln] = f2bf(v);
            }
        }
    }
}

// ---------- L1: h0(512) -> h1(256), elu. grid (8, 64); waves = K2 x N2 ------
// KSPLIT=2: 16 float4 weight loads in flight per wave; partials via LDS.
__global__ __launch_bounds__(256) void l1_kernel(const unsigned short* __restrict__ h0,
                                                 const int* __restrict__ tidx,
                                                 const float* __restrict__ w2,
                                                 const float* __restrict__ b2,
                                                 unsigned short* __restrict__ h1) {
    __shared__ f32x4 red[2][64];
    const int t = blockIdx.y;
    int2 sc = scan_teacher(tidx, t, nullptr);
    const int start = sc.x, count = sc.y;
    if (count == 0) return;
    const int lane = threadIdx.x & 63, wid = threadIdx.x >> 6;
    const int ln = lane & 15, kg = lane >> 4;
    const int kq = wid & 1, nq = wid >> 1;
    const int n0 = blockIdx.x * 32 + nq * 16;
    const int kbase = kq * 256;

    short8 bf[8];
    const float* wr = w2 + ((size_t)t * 256 + n0 + ln) * 512 + kbase;
#pragma unroll
    for (int k8 = 0; k8 < 8; ++k8) {
        int kb = k8 * 32 + kg * 8;
        bf[k8] = cvt8(*(const float4*)(wr + kb), *(const float4*)(wr + kb + 4));
    }
    const float bias = b2[(size_t)t * 256 + n0 + ln];

    for (int r0 = 0; r0 < count; r0 += 16) {
        const unsigned short* xr = h0 + (size_t)(start + r0 + ln) * 512 + kbase + kg * 8;
        f32x4 acc = {0.f, 0.f, 0.f, 0.f};
#pragma unroll
        for (int k8 = 0; k8 < 8; ++k8)
            acc = __builtin_amdgcn_mfma_f32_16x16x32_bf16(
                *(const short8*)(xr + k8 * 32), bf[k8], acc, 0, 0, 0);
        __syncthreads();
        if (kq == 1) red[nq][lane] = acc;
        __syncthreads();
        if (kq == 0) {
            f32x4 r = red[nq][lane];
            acc[0] += r[0]; acc[1] += r[1]; acc[2] += r[2]; acc[3] += r[3];
#pragma unroll
            for (int j = 0; j < 4; ++j) {
                int row = r0 + kg * 4 + j;
                if (row < count) {
                    float v = acc[j] + bias;
                    v = v > 0.f ? v : expm1f(v);
                    h1[(size_t)(start + row) * 256 + n0 + ln] = f2bf(v);
                }
            }
        }
    }
}

// ---------- L2+final fused: h1(256) -> h2(128, LDS) -> out(12), tanh --------
// grid (4 m-chunks, 64 t); 16-row chunk per iteration; h2 XOR-swizzled in LDS.
__global__ __launch_bounds__(256) void l2f_kernel(const unsigned short* __restrict__ h1,
                                                  const int* __restrict__ tidx,
                                                  const float* __restrict__ w4,
                                                  const float* __restrict__ b4,
                                                  const float* __restrict__ w6,
                                                  const float* __restrict__ b6,
                                                  float* __restrict__ out) {
    __shared__ int ord[BATCH];
    __shared__ char h2b[4096];            // 16 rows x 128 cols bf16, swizzled
    const int t = blockIdx.y;
    int2 sc = scan_teacher(tidx, t, ord);
    const int start = sc.x, count = sc.y;
    if ((int)blockIdx.x * 16 >= count) return;    // uniform; no-work blocks exit
    const int lane = threadIdx.x & 63, wid = threadIdx.x >> 6;
    const int ln = lane & 15, kg = lane >> 4;
    const int nq = wid;

    short8 bfA[2][8];
    float biasA[2];
#pragma unroll
    for (int sub = 0; sub < 2; ++sub) {
        const float* wr = w4 + ((size_t)t * 128 + nq * 32 + sub * 16 + ln) * 256;
#pragma unroll
        for (int k8 = 0; k8 < 8; ++k8) {
            int kb = k8 * 32 + kg * 8;
            bfA[sub][k8] = cvt8(*(const float4*)(wr + kb), *(const float4*)(wr + kb + 4));
        }
        biasA[sub] = b4[(size_t)t * 128 + nq * 32 + sub * 16 + ln];
    }
    short8 bf6[4];
    float bias6 = 0.f;
    if (wid == 0) {
        const float* wr = w6 + ((size_t)t * 12 + (ln < 12 ? ln : 0)) * 128;
#pragma unroll
        for (int kt = 0; kt < 4; ++kt) {
            int kb = kt * 32 + kg * 8;
            bf6[kt] = cvt8(*(const float4*)(wr + kb), *(const float4*)(wr + kb + 4));
        }
        if (ln < 12) bias6 = b6[(size_t)t * 12 + ln];
    }

    for (int mt = blockIdx.x; mt * 16 < count; mt += gridDim.x) {
        const int gr0 = start + mt * 16;
        // L2: this wave's 32 output cols for 16 sample rows
#pragma unroll
        for (int sub = 0; sub < 2; ++sub) {
            const unsigned short* xr = h1 + (size_t)(gr0 + ln) * 256 + kg * 8;
            f32x4 acc = {0.f, 0.f, 0.f, 0.f};
#pragma unroll
            for (int k8 = 0; k8 < 8; ++k8)
                acc = __builtin_amdgcn_mfma_f32_16x16x32_bf16(
                    *(const short8*)(xr + k8 * 32), bfA[sub][k8], acc, 0, 0, 0);
            int col = nq * 32 + sub * 16 + ln;
#pragma unroll
            for (int j = 0; j < 4; ++j) {
                int row = kg * 4 + j;             // sample within chunk
                float v = acc[j] + biasA[sub];
                v = v > 0.f ? v : expm1f(v);
                int byte = (row * 256 + col * 2) ^ ((row & 7) << 4);
                *(unsigned short*)(h2b + byte) = f2bf(v);
            }
        }
        __syncthreads();
        // final: wave 0 computes 16 samples x 12 outs, scatter to original rows
        if (wid == 0) {
            f32x4 acc = {0.f, 0.f, 0.f, 0.f};
#pragma unroll
            for (int kt = 0; kt < 4; ++kt) {
                int byte = (ln * 256 + (kt * 32 + kg * 8) * 2) ^ ((ln & 7) << 4);
                acc = __builtin_amdgcn_mfma_f32_16x16x32_bf16(
                    *(const short8*)(h2b + byte), bf6[kt], acc, 0, 0, 0);
            }
#pragma unroll
            for (int j = 0; j < 4; ++j) {
                int row = mt * 16 + kg * 4 + j;
                if (ln < 12 && row < count)
                    out[(size_t)ord[row] * 12 + ln] = tanhf(acc[j] + bias6);
            }
        }
        __syncthreads();
    }
}

extern "C" void kernel_launch(void* const* d_in, const int* in_sizes, int n_in,
                              void* d_out, int out_size, void* d_ws, size_t ws_size,
                              hipStream_t stream) {
    const float* obs = (const float*)d_in[0];
    const int* tidx  = (const int*)d_in[1];
    const float* w0  = (const float*)d_in[2];
    const float* b0  = (const float*)d_in[3];
    const float* w2  = (const float*)d_in[4];
    const float* b2  = (const float*)d_in[5];
    const float* w4  = (const float*)d_in[6];
    const float* b4  = (const float*)d_in[7];
    const float* w6  = (const float*)d_in[8];
    const float* b6  = (const float*)d_in[9];
    float* out = (float*)d_out;

    // bf16 activations in sorted space; +16 rows slack so tail A-fragment
    // overreads stay in-bounds (slack rows are finite garbage, never stored).
    const int ROWS = BATCH + 16;
    unsigned short* h0 = (unsigned short*)d_ws;           // ROWS*512
    unsigned short* h1 = h0 + (size_t)ROWS * 512;         // ROWS*256

    l0_kernel<<<dim3(16, NTEACH), 256, 0, stream>>>(obs, tidx, w0, b0, h0);
    l1_kernel<<<dim3(8, NTEACH), 256, 0, stream>>>(h0, tidx, w2, b2, h1);
    l2f_kernel<<<dim3(4, NTEACH), 256, 0, stream>>>(h1, tidx, w4, b4, w6, b6, out);
}